// Round 1
// baseline (699.338 us; speedup 1.0000x reference)
//
#include <hip/hip_runtime.h>
#include <hip/hip_bf16.h>
#include <math.h>

#define B_  32
#define T_  2048
#define H_  1024
#define LD_ 1024
#define M_  (B_*T_)   // 65536 rows of enc

typedef __attribute__((ext_vector_type(8))) short bf16x8;
typedef __attribute__((ext_vector_type(4))) float f32x4;

__device__ __forceinline__ void async_copy16(void* lds, const void* g) {
  __builtin_amdgcn_global_load_lds(
      (const __attribute__((address_space(1))) void*)g,
      (__attribute__((address_space(3))) void*)lds, 16, 0, 0);
}

// W2 [H, LD] fp32 -> w2p bf16 k-grouped: w2p[(k/8)*LD*8 + n*8 + (k%8)]
__global__ void convert_w2(const float* __restrict__ W2, __hip_bfloat16* __restrict__ w2p) {
  int idx = blockIdx.x * 256 + threadIdx.x;        // 128K threads
  int kg = idx >> 10, n = idx & 1023;
  __align__(16) __hip_bfloat16 h[8];
#pragma unroll
  for (int j = 0; j < 8; ++j)
    h[j] = __float2bfloat16(W2[(size_t)(kg * 8 + j) * LD_ + n]);
  *reinterpret_cast<uint4*>(&w2p[(size_t)kg * (LD_ * 8) + n * 8]) =
      *reinterpret_cast<const uint4*>(h);
}

// dec_w[b][l] = sum_h dec[b][h] * W1[h][l] + b1[l]
__global__ void dec_proj(const float* __restrict__ dec, const float* __restrict__ W1,
                         const float* __restrict__ b1, float* __restrict__ dec_w) {
  __shared__ float sdec[H_];
  int bb = blockIdx.x >> 2;
  int l = (blockIdx.x & 3) * 256 + threadIdx.x;
  for (int i = threadIdx.x; i < H_; i += 256) sdec[i] = dec[bb * H_ + i];
  __syncthreads();
  float a0 = 0.f, a1 = 0.f, a2 = 0.f, a3 = 0.f;
  for (int h = 0; h < H_; h += 4) {
    a0 += sdec[h + 0] * W1[(h + 0) * LD_ + l];
    a1 += sdec[h + 1] * W1[(h + 1) * LD_ + l];
    a2 += sdec[h + 2] * W1[(h + 2) * LD_ + l];
    a3 += sdec[h + 3] * W1[(h + 3) * LD_ + l];
  }
  dec_w[bb * LD_ + l] = (a0 + a1) + (a2 + a3) + b1[l];
}

// Fused: enc_w tile via bf16 MFMA, then score[m] += sum_n tanh(dec_w[b,n]*(enc_w+b2[n]))*V[n]
// Tile: 128(M) x 256(N), BK=32, 4 waves 2x2, wave tile 64x128 = acc[4][8].
// v2: double-buffered LDS + depth-1 prefetch (T3 minimum 2-phase),
//     XOR bank-swizzle on A stage writes/reads, XCD-aware block swizzle (T1).
__global__ __launch_bounds__(256, 2)
void score_gemm(const float* __restrict__ enc,
                const __hip_bfloat16* __restrict__ w2p,
                const float* __restrict__ dec_w,
                const float* __restrict__ b2,
                const float* __restrict__ V,
                float* __restrict__ score) {
  __shared__ __align__(16) __hip_bfloat16 Asm[2][4][128][8];  // [buf][kg][m][k%8], 16KB
  __shared__ __align__(16) __hip_bfloat16 Bsm[2][4][256][8];  // [buf][kg][n][k%8], 32KB

  const int tid  = threadIdx.x;
  const int lane = tid & 63;
  const int wave = tid >> 6;
  const int wm = wave >> 1, wn = wave & 1;       // 2x2 wave grid
  // T1: XCD-aware swizzle. nwg = 2048, nwg%8==0 -> simple bijective remap.
  // Raw linear id round-robins over 8 XCDs; remap so each XCD owns 256
  // consecutive swz ids = 64 full mb-quads (the 4 nb blocks sharing one
  // enc tile land on the SAME XCD L2).
  const int bid = blockIdx.y * gridDim.x + blockIdx.x;
  const int swz = (bid & 7) * 256 + (bid >> 3);
  const int mb = swz >> 2, nb = swz & 3;
  const int row0 = mb * 128, col0 = nb * 256;
  const int q = lane >> 4, c15 = lane & 15;

  f32x4 acc[4][8] = {};

  const int sm  = tid >> 2;   // staging row within half-tile
  const int skg = tid & 3;    // staging k-group
  const int sx  = skg * 2;    // XOR row-swizzle for A-stage bank conflicts

  const size_t arow0 = (size_t)(row0 + sm) * H_ + skg * 8;
  const size_t arow1 = (size_t)(row0 + 64 + sm) * H_ + skg * 8;

  float4 pf[4];  // in-flight A prefetch (fp32)

  auto LOADA = [&](int k0) {
    pf[0] = *reinterpret_cast<const float4*>(enc + arow0 + k0);
    pf[1] = *reinterpret_cast<const float4*>(enc + arow0 + k0 + 4);
    pf[2] = *reinterpret_cast<const float4*>(enc + arow1 + k0);
    pf[3] = *reinterpret_cast<const float4*>(enc + arow1 + k0 + 4);
  };
  auto CVTW = [&](int buf) {
    __align__(16) __hip_bfloat16 h[8];
    h[0] = __float2bfloat16(pf[0].x); h[1] = __float2bfloat16(pf[0].y);
    h[2] = __float2bfloat16(pf[0].z); h[3] = __float2bfloat16(pf[0].w);
    h[4] = __float2bfloat16(pf[1].x); h[5] = __float2bfloat16(pf[1].y);
    h[6] = __float2bfloat16(pf[1].z); h[7] = __float2bfloat16(pf[1].w);
    *reinterpret_cast<uint4*>(&Asm[buf][skg][sm ^ sx][0]) =
        *reinterpret_cast<const uint4*>(h);
    h[0] = __float2bfloat16(pf[2].x); h[1] = __float2bfloat16(pf[2].y);
    h[2] = __float2bfloat16(pf[2].z); h[3] = __float2bfloat16(pf[2].w);
    h[4] = __float2bfloat16(pf[3].x); h[5] = __float2bfloat16(pf[3].y);
    h[6] = __float2bfloat16(pf[3].z); h[7] = __float2bfloat16(pf[3].w);
    *reinterpret_cast<uint4*>(&Asm[buf][skg][(64 + sm) ^ sx][0]) =
        *reinterpret_cast<const uint4*>(h);
  };
  auto GLOADB = [&](int buf, int k0) {
    char* bbase = (char*)&Bsm[buf][0][0][0] + tid * 16;
    const char* gbase = (const char*)w2p + ((size_t)(k0 >> 3)) * (LD_ * 8 * 2)
                        + (size_t)col0 * 16 + tid * 16;
#pragma unroll
    for (int p = 0; p < 4; ++p)
      async_copy16(bbase + p * 4096, gbase + (size_t)p * (LD_ * 8 * 2));
  };

  // prologue: stage tile 0 into buf 0
  LOADA(0);
  GLOADB(0, 0);
  CVTW(0);            // compiler waits only the 4 A loads (vmcnt(4)), B stays in flight
  __syncthreads();    // drains B gload_lds + A ds_writes

  for (int t = 0; t < 32; ++t) {
    const int cur = t & 1;
    if (t < 31) {
      LOADA((t + 1) * 32);          // issue next A loads (regs) — latency hides under MFMA
      GLOADB(cur ^ 1, (t + 1) * 32);// issue next B gload_lds into other buffer
    }
    bf16x8 af[4], bfr[8];
#pragma unroll
    for (int i = 0; i < 4; ++i)
      af[i] = *reinterpret_cast<const bf16x8*>(
          &Asm[cur][q][(wm * 64 + i * 16 + c15) ^ (q * 2)][0]);
#pragma unroll
    for (int j = 0; j < 8; ++j)
      bfr[j] = *reinterpret_cast<const bf16x8*>(
          &Bsm[cur][q][wn * 128 + j * 16 + c15][0]);
#pragma unroll
    for (int i = 0; i < 4; ++i)
#pragma unroll
      for (int j = 0; j < 8; ++j)
        acc[i][j] = __builtin_amdgcn_mfma_f32_16x16x32_bf16(af[i], bfr[j], acc[i][j], 0, 0, 0);
    if (t < 31) CVTW(cur ^ 1);      // cvt+write after MFMA: A load latency already covered
    __syncthreads();                // one vmcnt(0)+barrier per K-tile
  }

  // --- fused epilogue: tanh + V-dot + row reduction ---
  const int bb = row0 >> 11;   // batch index (2048 % 128 == 0, no straddle)
  float b2v[8], dwv[8], Vv[8];
#pragma unroll
  for (int j = 0; j < 8; ++j) {
    int n = col0 + wn * 128 + j * 16 + c15;
    b2v[j] = b2[n];
    dwv[j] = dec_w[bb * LD_ + n];
    Vv[j]  = V[n];
  }
#pragma unroll
  for (int i = 0; i < 4; ++i) {
#pragma unroll
    for (int r = 0; r < 4; ++r) {
      float v = 0.f;
#pragma unroll
      for (int j = 0; j < 8; ++j) {
        float e = acc[i][j][r] + b2v[j];          // enc_w + b2  (row=q*4+r, col=c15)
        v += tanhf(dwv[j] * e) * Vv[j];
      }
      v += __shfl_xor(v, 1);
      v += __shfl_xor(v, 2);
      v += __shfl_xor(v, 4);
      v += __shfl_xor(v, 8);                      // sum 16 cols within quad
      if (c15 == 0) {
        int row = row0 + wm * 64 + i * 16 + q * 4 + r;
        atomicAdd(&score[row], v);
      }
    }
  }
}

// softmax over T per batch; bV is softmax-invariant (scalar), omitted
__global__ void softmax_k(const float* __restrict__ score, float* __restrict__ attn) {
  int bb = blockIdx.x;
  int tid = threadIdx.x;
  int lane = tid & 63, wave = tid >> 6;
  __shared__ float red[4];
  float v[8];
  float mx = -3.4e38f;
#pragma unroll
  for (int i = 0; i < 8; ++i) {
    v[i] = score[bb * T_ + i * 256 + tid];
    mx = fmaxf(mx, v[i]);
  }
#pragma unroll
  for (int m = 32; m >= 1; m >>= 1) mx = fmaxf(mx, __shfl_xor(mx, m));
  if (lane == 0) red[wave] = mx;
  __syncthreads();
  mx = fmaxf(fmaxf(red[0], red[1]), fmaxf(red[2], red[3]));
  __syncthreads();
  float s = 0.f;
#pragma unroll
  for (int i = 0; i < 8; ++i) { v[i] = __expf(v[i] - mx); s += v[i]; }
#pragma unroll
  for (int m = 32; m >= 1; m >>= 1) s += __shfl_xor(s, m);
  if (lane == 0) red[wave] = s;
  __syncthreads();
  s = red[0] + red[1] + red[2] + red[3];
  float inv = 1.f / s;
#pragma unroll
  for (int i = 0; i < 8; ++i) attn[bb * T_ + i * 256 + tid] = v[i] * inv;
}

// context[b][h] = sum_t attn[b][t] * enc[b][t][h]
// v2: float4 loads (16B/lane), 8-deep unroll for in-flight bytes; t split 16-way.
__global__ __launch_bounds__(256)
void context_k(const float* __restrict__ enc, const float* __restrict__ attn,
               float* __restrict__ ctx) {
  const int bb = blockIdx.y;
  const int t0 = blockIdx.x * 128;                 // 16 chunks x 128 t
  __shared__ float sat[128];
  if (threadIdx.x < 128) sat[threadIdx.x] = attn[bb * T_ + t0 + threadIdx.x];
  __syncthreads();
  const float4* base = reinterpret_cast<const float4*>(
      enc + ((size_t)bb * T_ + t0) * H_) + threadIdx.x;   // 256 threads cover full H row
  f32x4 a0 = {}, a1 = {}, a2 = {}, a3 = {};
  for (int t = 0; t < 128; t += 8) {
    float4 v[8];
#pragma unroll
    for (int u = 0; u < 8; ++u) v[u] = base[(size_t)(t + u) * (H_ / 4)];
#pragma unroll
    for (int u = 0; u < 8; ++u) {
      float a = sat[t + u];
      f32x4& d = (u & 2) ? ((u & 1) ? a3 : a2) : ((u & 1) ? a1 : a0);
      d[0] += a * v[u].x; d[1] += a * v[u].y;
      d[2] += a * v[u].z; d[3] += a * v[u].w;
    }
  }
  const int h = threadIdx.x * 4;
  atomicAdd(&ctx[bb * H_ + h + 0], (a0[0] + a1[0]) + (a2[0] + a3[0]));
  atomicAdd(&ctx[bb * H_ + h + 1], (a0[1] + a1[1]) + (a2[1] + a3[1]));
  atomicAdd(&ctx[bb * H_ + h + 2], (a0[2] + a1[2]) + (a2[2] + a3[2]));
  atomicAdd(&ctx[bb * H_ + h + 3], (a0[3] + a1[3]) + (a2[3] + a3[3]));
}

extern "C" void kernel_launch(void* const* d_in, const int* in_sizes, int n_in,
                              void* d_out, int out_size, void* d_ws, size_t ws_size,
                              hipStream_t stream) {
  const float* enc = (const float*)d_in[0];
  const float* dec = (const float*)d_in[1];
  const float* W1  = (const float*)d_in[2];
  const float* b1  = (const float*)d_in[3];
  const float* W2  = (const float*)d_in[4];
  const float* b2  = (const float*)d_in[5];
  const float* V   = (const float*)d_in[6];
  // d_in[7] = bV: softmax-invariant additive scalar -> ignored.

  char* ws = (char*)d_ws;
  __hip_bfloat16* w2p = (__hip_bfloat16*)ws;                       // 2 MB
  float* dec_w = (float*)(ws + (2u << 20));                        // 128 KB
  float* score = (float*)(ws + (2u << 20) + (128u << 10));         // 256 KB

  float* out  = (float*)d_out;
  float* ctx  = out;              // [B, H]   = 32768 floats
  float* attn = out + B_ * H_;    // [B, T, 1] = 65536 floats

  hipMemsetAsync(score, 0, (size_t)M_ * sizeof(float), stream);
  hipMemsetAsync(ctx, 0, (size_t)B_ * H_ * sizeof(float), stream);

  convert_w2<<<(H_ * LD_ / 8) / 256, 256, 0, stream>>>(W2, w2p);
  dec_proj<<<B_ * 4, 256, 0, stream>>>(dec, W1, b1, dec_w);
  score_gemm<<<dim3(LD_ / 256, M_ / 128), 256, 0, stream>>>(enc, w2p, dec_w, b2, V, score);
  softmax_k<<<B_, 256, 0, stream>>>(score, attn);
  context_k<<<dim3(16, B_), 256, 0, stream>>>(enc, attn, ctx);
}